// Round 16
// baseline (178.575 us; speedup 1.0000x reference)
//
#include <hip/hip_runtime.h>
#include <hip/hip_bf16.h>
#include <math.h>

#define BB 8
#define NN 512
#define DD 256
#define BNT 4096   // B*N

typedef __attribute__((ext_vector_type(8))) short short8;
typedef __attribute__((ext_vector_type(4))) float f32x4;

// Workspace layout (float offsets). ~18 MB.  (= round-0 baseline layout)
#define OFF_S0B   0u          // bf16 [4096][256]      s0 row-major (gemmT B)
#define OFF_TT    524288u     // bf16 [8][256][3072]   TT[b][e][r*512+i] = T_r[i][e]+relb_r[e]
#define OFF_WCT   6815744u    // bf16 [256][1536]      WcT[e][r*256+d] = relW[r][d][e]
#define OFF_WBT   7012352u    // bf16 [1024][256]      Wbig^T (c rows, k=d)
#define OFF_BB    7143424u    // fp32 [1024]           h1b|outb
#define OFF_REL   7144448u    // u8   [8][512][512]    relation codes (self=6)

// d_out layout (floats)
#define OUT0_OFF   0u        // output  [8][512][256]
#define INTERP_OFF 1048576u  // interp  [3][4096]
#define SYM_OFF    1060864u  // symbols [8][512][256]

__device__ __forceinline__ float gelu_exact(float x) {
    return 0.5f * x * (1.0f + erff(x * 0.70710678118654752f));
}

__device__ __forceinline__ ushort f2bf(float x) {
    __hip_bfloat16 h = __float2bfloat16(x);
    union { __hip_bfloat16 b; ushort u; } cv;
    cv.b = h;
    return cv.u;
}

// Branch-free classification (reference if/elif priority, applied in reverse).
__device__ __forceinline__ int rel_of(float dx, float dy) {
    int r = (fabsf(dx) < 0.3f && fabsf(dy) < 0.3f) ? 4 : 5;
    r = (dx >  0.5f) ? 3 : r;
    r = (dx < -0.5f) ? 2 : r;
    r = (dy < -0.5f) ? 1 : r;
    r = (dy >  0.5f) ? 0 : r;
    return r;
}

// ====== 64x64-tile MFMA core (4 waves 2x2), double-buffered LDS ===========
// = the 134.9 µs round-11 core, with 2-DEEP REGISTER PREFETCH: LOADS(i+2)
// issued at iter i, so STAGE(i+1)'s vmcnt-wait lands >=1 full iteration
// after issue (load latency hidden). LDS dbuf/barriers unchanged.
// Fragment layout (m89/m91 verified): A: m=lane&15,k=quad*8+j; B: n=lane&15;
// C/D: col=lane&15, row=quad*4+reg.
#define TILE_IDS()                                             \
    const int lane = tid & 63, w = tid >> 6;                   \
    const int wm = w >> 1, wn = w & 1;                         \
    const int quad = lane >> 4, l15 = lane & 15;               \
    const int sm = tid >> 2, sq = tid & 3;

#define MFMA_STEP(Abuf, Bbuf)                                                \
    {                                                                        \
        short8 af[2], bfr[2];                                                \
        _Pragma("unroll")                                                    \
        for (int mt = 0; mt < 2; mt++)                                       \
            af[mt] = *(const short8*)&(Abuf)[(quad * 64 + wm * 32 + mt * 16 + l15) * 8]; \
        _Pragma("unroll")                                                    \
        for (int nt = 0; nt < 2; nt++)                                       \
            bfr[nt] = *(const short8*)&(Bbuf)[(quad * 64 + wn * 32 + nt * 16 + l15) * 8]; \
        _Pragma("unroll")                                                    \
        for (int mt = 0; mt < 2; mt++)                                       \
            _Pragma("unroll")                                                \
            for (int nt = 0; nt < 2; nt++)                                   \
                acc[mt][nt] = __builtin_amdgcn_mfma_f32_16x16x32_bf16(       \
                    af[mt], bfr[nt], acc[mt][nt], 0, 0, 0);                  \
    }

#define ACC_INIT()                                             \
    f32x4 acc[2][2];                                           \
    _Pragma("unroll") for (int mt = 0; mt < 2; mt++)           \
    _Pragma("unroll") for (int nt = 0; nt < 2; nt++)           \
        acc[mt][nt] = (f32x4){0.f, 0.f, 0.f, 0.f};

// front block ranges (round-11 verified, 134.9 µs)
#define FB_TILE  0      // 160 blocks: 64x64 transpose tiles (WcT 96, h1W 48, outW 16)
#define FB_OUTI  160    // 12 blocks:  outI init (float4)
#define FB_BBIG  172    // 1 block:    bbig init
#define FB_GATH  173    // 1024 blocks: gather (4 rows/block, float4)
#define FB_CLS   1197   // 512 blocks: classify
#define FB_TOTAL 1709

// ---------------------------------------------------------------- front ---
// [= round-11 verbatim]
__global__ __launch_bounds__(256) void front_kernel(
    const int* __restrict__ ids, const float* __restrict__ positions,
    const float* __restrict__ symt, const float* __restrict__ layt,
    const float* __restrict__ relW, const float* __restrict__ h1W,
    const float* __restrict__ outW, const float* __restrict__ h1b,
    const float* __restrict__ outb, const float* __restrict__ h2b,
    ushort* __restrict__ WcT, ushort* __restrict__ WbT,
    float* __restrict__ bbig, float* __restrict__ outI,
    float* __restrict__ symOut, ushort* __restrict__ s0b,
    unsigned char* __restrict__ rel)
{
    __shared__ float shbuf[64 * 65];    // 16.6 KB transpose tile / classify px,py
    int blk = blockIdx.x, tid = threadIdx.x;
    if (blk < FB_OUTI) {
        int kl = tid & 63, g4 = tid >> 6;
        const float* src; int srow, scol;
        ushort* dst; int drow, dstride, dcol;
        if (blk < 96) {                         // relW [1536][256] -> WcT[e][rd]
            int t = blk, rdt = t >> 2, et = t & 3;
            src = relW; srow = rdt * 64; scol = et * 64;
            dst = WcT; drow = et * 64; dstride = 1536; dcol = rdt * 64;
        } else if (blk < 144) {                 // h1W [r][256 d][256 e] -> WbT[r*256+e][d]
            int t = blk - 96, r = t >> 4, dt = (t >> 2) & 3, et = t & 3;
            src = h1W + (size_t)r * DD * DD; srow = dt * 64; scol = et * 64;
            dst = WbT; drow = r * 256 + et * 64; dstride = 256; dcol = dt * 64;
        } else {                                // outW [256 d][256 o] -> WbT[768+o][d]
            int t = blk - 144, dt = t >> 2, et = t & 3;
            src = outW; srow = dt * 64; scol = et * 64;
            dst = WbT; drow = 768 + et * 64; dstride = 256; dcol = dt * 64;
        }
#pragma unroll
        for (int p = 0; p < 16; p++) {
            int rl = p * 4 + g4;
            shbuf[rl * 65 + kl] = src[(size_t)(srow + rl) * 256 + scol + kl];
        }
        __syncthreads();
#pragma unroll
        for (int q = 0; q < 16; q++) {
            int el = q * 4 + g4;
            dst[(size_t)(drow + el) * dstride + dcol + kl] = f2bf(shbuf[kl * 65 + el]);
        }
    } else if (blk < FB_BBIG) {
        int idx = (blk - FB_OUTI) * 256 + tid;   // [0, 3072) float4s of outI
        float v = h2b[idx >> 10];
        ((float4*)outI)[idx] = (float4){v, v, v, v};
    } else if (blk < FB_GATH) {
        ((float4*)bbig)[tid] = (tid < 192) ? ((const float4*)h1b)[tid]
                                           : ((const float4*)outb)[tid - 192];
    } else if (blk < FB_CLS) {
        int row = (blk - FB_GATH) * 4 + (tid >> 6); // 4 rows/block
        int d = (tid & 63) * 4;
        int id = ids[row];
        float4 a = *(const float4*)&symt[(size_t)id * DD + d];
        float4 c = *(const float4*)&layt[(size_t)id * DD + d];
        float4 v = {a.x + c.x, a.y + c.y, a.z + c.z, a.w + c.w};
        *(float4*)&symOut[(size_t)row * DD + d] = v;
        union { ushort u[4]; uint2 q; } p;
        p.u[0] = f2bf(v.x); p.u[1] = f2bf(v.y); p.u[2] = f2bf(v.z); p.u[3] = f2bf(v.w);
        *(uint2*)&s0b[(size_t)row * DD + d] = p.q;
    } else {
        float* px = shbuf;
        float* py = shbuf + NN;
        int blk2 = blk - FB_CLS;                 // [0,512)
        int b = blk2 >> 6;
        int j0 = (blk2 & 63) << 3;
        int jl = tid >> 5, sub = tid & 31;       // 8 j's x 32 workers x 16 i's
        for (int i = tid; i < NN; i += 256) {
            float2 p = ((const float2*)positions)[b * NN + i];
            px[i] = p.x; py[i] = p.y;
        }
        __syncthreads();
        int j = j0 + jl;
        float xj = px[j], yj = py[j];
        union { unsigned char u8[16]; uint4 v; } codes;
#pragma unroll
        for (int t = 0; t < 16; t++) {
            int i = sub * 16 + t;
            int r = rel_of(xj - px[i], yj - py[i]);
            r = (i == j) ? 6 : r;
            codes.u8[t] = (unsigned char)r;
        }
        *(uint4*)&rel[((size_t)(b * NN + j)) * NN + sub * 16] = codes.v;
    }
}

// ----------------------------------------------------------------- gemmT --
// TT[b][e][r*512+i] = sum_d relW[r][d][e]*s0[b][i][d] + relb[r][e]
// Grid (8,24,8) = 1536 blocks; 2-deep register prefetch.
__global__ __launch_bounds__(256) void gemmT_kernel(
    const ushort* __restrict__ WcT, const ushort* __restrict__ s0b,
    const float* __restrict__ relb, ushort* __restrict__ TT)
{
    __shared__ ushort Als[2][2048], Bls[2][2048];
    int tid = threadIdx.x;
    int b = blockIdx.z;
    int rowM0 = blockIdx.y * 64;           // in [0,1536): r*256+e
    int col0 = blockIdx.x * 64;            // i tile
    int r = rowM0 >> 8, e0 = rowM0 & 255;
    TILE_IDS();
    ACC_INIT();
    const ushort* gA = WcT + (size_t)(e0 + sm) * 1536 + r * 256 + sq * 8;
    const ushort* gB = s0b + ((size_t)(b * NN) + col0 + sm) * DD + sq * 8;
    const int lo = (sq * 64 + sm) * 8;

    uint4 avP[2], bvP[2];
    avP[0] = *(const uint4*)gA;        bvP[0] = *(const uint4*)gB;
    avP[1] = *(const uint4*)(gA + 32); bvP[1] = *(const uint4*)(gB + 32);
    *(uint4*)&Als[0][lo] = avP[0];
    *(uint4*)&Bls[0][lo] = bvP[0];
#pragma unroll
    for (int i = 0; i < 8; i++) {
        __syncthreads();
        if (i < 6) {   // LOADS(i+2) overwrite slot i&1 (already staged)
            avP[i & 1] = *(const uint4*)(gA + (i + 2) * 32);
            bvP[i & 1] = *(const uint4*)(gB + (i + 2) * 32);
        }
        MFMA_STEP(Als[i & 1], Bls[i & 1]);
        if (i < 7) {
            *(uint4*)&Als[(i + 1) & 1][lo] = avP[(i + 1) & 1];
            *(uint4*)&Bls[(i + 1) & 1][lo] = bvP[(i + 1) & 1];
        }
    }
#pragma unroll
    for (int mt = 0; mt < 2; mt++)
#pragma unroll
        for (int nt = 0; nt < 2; nt++)
#pragma unroll
            for (int v = 0; v < 4; v++) {
                int e = e0 + wm * 32 + mt * 16 + quad * 4 + v;
                int i = col0 + wn * 32 + nt * 16 + l15;
                TT[((size_t)(b * DD) + e) * 3072 + r * 512 + i] =
                    f2bf(acc[mt][nt][v] + relb[r * DD + e]);
            }
}

// ------------------------------------------------------------- agg gemm ---
// symOut[b*512+j][e] += sum_{r,i} 1[rel(i,j)=r] * TT[b][e][r*512+i]
// One-hot A from u8 codes; 3 K-slices (r-pairs, K=1024), grid (4,8,24).
// 2-deep register prefetch; atomicAdd into symOut (= s0 base from front).
__global__ __launch_bounds__(256) void agg_gemm(
    const unsigned char* __restrict__ rel, const ushort* __restrict__ TT,
    float* __restrict__ symOut)
{
    __shared__ ushort Als[2][2048], Bls[2][2048];
    int tid = threadIdx.x;
    int z = blockIdx.z;
    int b = z / 3, rg = z - b * 3;
    int row0 = blockIdx.y * 64, col0 = blockIdx.x * 64;
    TILE_IDS();
    ACC_INIT();
    const unsigned char* gC = rel + ((size_t)(b * NN + row0 + sm)) * NN;
    const ushort* gB = TT + ((size_t)(b * DD) + col0 + sm) * 3072 + rg * 1024 + sq * 8;
    const int lo = (sq * 64 + sm) * 8;

#define AGG_LOADS(i, cw, bv)                                        \
    cw = *(const uint2*)(gC + (((i) * 32 + sq * 8) & 511));         \
    bv = *(const uint4*)(gB + (i) * 32);

#define AGG_STAGE(i, cw, bv, buf)                                   \
    {                                                               \
        int rr_ = 2 * rg + (((i) * 32) >> 9);                       \
        union alignas(16) { ushort u[8]; uint4 v; } am;             \
        _Pragma("unroll")                                           \
        for (int t = 0; t < 8; t++) {                               \
            unsigned int word = (t < 4) ? cw.x : cw.y;              \
            unsigned int code = (word >> (8 * (t & 3))) & 255u;     \
            am.u[t] = (code == (unsigned)rr_) ? 0x3F80 : 0;         \
        }                                                           \
        *(uint4*)&Als[buf][lo] = am.v;                              \
        *(uint4*)&Bls[buf][lo] = bv;                                \
    }

    uint2 cwP[2]; uint4 bvP[2];
    AGG_LOADS(0, cwP[0], bvP[0]);
    AGG_LOADS(1, cwP[1], bvP[1]);
    AGG_STAGE(0, cwP[0], bvP[0], 0);
#pragma unroll
    for (int i = 0; i < 32; i++) {
        __syncthreads();
        if (i < 30) { AGG_LOADS(i + 2, cwP[i & 1], bvP[i & 1]); }
        MFMA_STEP(Als[i & 1], Bls[i & 1]);
        if (i < 31) { AGG_STAGE(i + 1, cwP[(i + 1) & 1], bvP[(i + 1) & 1], (i + 1) & 1); }
    }
#undef AGG_LOADS
#undef AGG_STAGE
#pragma unroll
    for (int mt = 0; mt < 2; mt++)
#pragma unroll
        for (int nt = 0; nt < 2; nt++)
#pragma unroll
            for (int v = 0; v < 4; v++) {
                int j = row0 + wm * 32 + mt * 16 + quad * 4 + v;
                int e = col0 + wn * 32 + nt * 16 + l15;
                atomicAdd(&symOut[((size_t)(b * NN) + j) * DD + e], acc[mt][nt][v]);
            }
}

// ----------------------------------------------------------------- gemm2 --
// symOut(fp32, bf16 at staging) @ Wbig^T. Col tiles <768: gelu + fused
// interp reduce (atomicAdd into outI pre-loaded with h2b). Else: out0.
// Grid (16,64); 2-deep register prefetch.
__global__ __launch_bounds__(256) void gemm2_kernel(
    const float* __restrict__ symOut, const ushort* __restrict__ WbT,
    const float* __restrict__ bbig, const float* __restrict__ h2W,
    float* __restrict__ out0, float* __restrict__ outI)
{
    __shared__ ushort Als[2][2048], Bls[2][2048];
    int tid = threadIdx.x;
    int row0 = blockIdx.y * 64, col0 = blockIdx.x * 64;
    TILE_IDS();
    ACC_INIT();
    const float*  gA = symOut + (size_t)(row0 + sm) * DD + sq * 8;
    const ushort* gB = WbT    + (size_t)(col0 + sm) * DD + sq * 8;
    const int lo = (sq * 64 + sm) * 8;

#define G2_LOADS(i, a0, a1, bv)                                     \
    a0 = *(const float4*)(gA + (i) * 32);                           \
    a1 = *(const float4*)(gA + (i) * 32 + 4);                       \
    bv = *(const uint4*)(gB + (i) * 32);

#define G2_STAGE(a0, a1, bv, buf)                                   \
    {                                                               \
        union alignas(16) { ushort u[8]; uint4 v; } am;             \
        am.u[0] = f2bf(a0.x); am.u[1] = f2bf(a0.y);                 \
        am.u[2] = f2bf(a0.z); am.u[3] = f2bf(a0.w);                 \
        am.u[4] = f2bf(a1.x); am.u[5] = f2bf(a1.y);                 \
        am.u[6] = f2bf(a1.z); am.u[7] = f2bf(a1.w);                 \
        *(uint4*)&Als[buf][lo] = am.v;                              \
        *(uint4*)&Bls[buf][lo] = bv;                                \
    }

    float4 a0P[2], a1P[2]; uint4 bvP[2];
    G2_LOADS(0, a0P[0], a1P[0], bvP[0]);
    G2_LOADS(1, a0P[1], a1P[1], bvP[1]);
    G2_STAGE(a0P[0], a1P[0], bvP[0], 0);
#pragma unroll
    for (int i = 0; i < 8; i++) {
        __syncthreads();
        if (i < 6) { G2_LOADS(i + 2, a0P[i & 1], a1P[i & 1], bvP[i & 1]); }
        MFMA_STEP(Als[i & 1], Bls[i & 1]);
        if (i < 7) { G2_STAGE(a0P[(i + 1) & 1], a1P[(i + 1) & 1], bvP[(i + 1) & 1], (i + 1) & 1); }
    }
#undef G2_LOADS
#undef G2_STAGE
    if (col0 >= 768) {
#pragma unroll
        for (int nt = 0; nt < 2; nt++) {
            int c = col0 + wn * 32 + nt * 16 + l15;
            float bb = bbig[c];
#pragma unroll
            for (int mt = 0; mt < 2; mt++)
#pragma unroll
                for (int v = 0; v < 4; v++) {
                    int row = row0 + wm * 32 + mt * 16 + quad * 4 + v;
                    out0[(size_t)row * DD + (c - 768)] = acc[mt][nt][v] + bb;
                }
        }
    } else {
        int head = col0 >> 8;
        float part[2][4];
#pragma unroll
        for (int mt = 0; mt < 2; mt++)
#pragma unroll
            for (int v = 0; v < 4; v++) part[mt][v] = 0.f;
#pragma unroll
        for (int nt = 0; nt < 2; nt++) {
            int c = col0 + wn * 32 + nt * 16 + l15;
            float bb = bbig[c];
            float w2 = h2W[c];
#pragma unroll
            for (int mt = 0; mt < 2; mt++)
#pragma unroll
                for (int v = 0; v < 4; v++)
                    part[mt][v] += gelu_exact(acc[mt][nt][v] + bb) * w2;
        }
#pragma unroll
        for (int mt = 0; mt < 2; mt++)
#pragma unroll
            for (int v = 0; v < 4; v++) {
                float p = part[mt][v];
                p += __shfl_xor(p, 1); p += __shfl_xor(p, 2);
                p += __shfl_xor(p, 4); p += __shfl_xor(p, 8);
                if (l15 == 0) {
                    int row = row0 + wm * 32 + mt * 16 + quad * 4 + v;
                    atomicAdd(&outI[head * BNT + row], p);
                }
            }
    }
}

// ---------------------------------------------------------------- launch --
extern "C" void kernel_launch(void* const* d_in, const int* in_sizes, int n_in,
                              void* d_out, int out_size, void* d_ws, size_t ws_size,
                              hipStream_t stream)
{
    const int*   ids  = (const int*)d_in[0];
    const float* pos  = (const float*)d_in[1];
    const float* symt = (const float*)d_in[2];
    const float* layt = (const float*)d_in[3];
    const float* relW = (const float*)d_in[4];
    const float* relb = (const float*)d_in[5];
    const float* h1W  = (const float*)d_in[6];
    const float* h1b  = (const float*)d_in[7];
    const float* h2W  = (const float*)d_in[8];
    const float* h2b  = (const float*)d_in[9];
    const float* outW = (const float*)d_in[10];
    const float* outb = (const float*)d_in[11];
    float* out = (float*)d_out;
    float* ws  = (float*)d_ws;

    ushort* s0b  = (ushort*)(ws + OFF_S0B);
    ushort* TT   = (ushort*)(ws + OFF_TT);
    ushort* WcT  = (ushort*)(ws + OFF_WCT);
    ushort* WbT  = (ushort*)(ws + OFF_WBT);
    float*  bbig = ws + OFF_BB;
    unsigned char* rel = (unsigned char*)(ws + OFF_REL);

    front_kernel<<<FB_TOTAL, 256, 0, stream>>>(ids, pos, symt, layt, relW, h1W, outW,
                                               h1b, outb, h2b, WcT, WbT, bbig,
                                               out + INTERP_OFF, out + SYM_OFF, s0b, rel);
    gemmT_kernel<<<dim3(8, 24, 8), 256, 0, stream>>>(WcT, s0b, relb, TT);
    agg_gemm<<<dim3(4, 8, 24), 256, 0, stream>>>(rel, TT, out + SYM_OFF);
    gemm2_kernel<<<dim3(16, 64), 256, 0, stream>>>(out + SYM_OFF, WbT,
                                                   bbig, h2W,
                                                   out + OUT0_OFF, out + INTERP_OFF);
}

// Round 17
// 132.202 us; speedup vs baseline: 1.3508x; 1.3508x over previous
//
#include <hip/hip_runtime.h>
#include <hip/hip_bf16.h>
#include <math.h>

#define BB 8
#define NN 512
#define DD 256
#define BNT 4096   // B*N

typedef __attribute__((ext_vector_type(8))) short short8;
typedef __attribute__((ext_vector_type(4))) float f32x4;

// Workspace layout (float offsets). ~18 MB.  (= round-0 baseline layout)
#define OFF_S0B   0u          // bf16 [4096][256]      s0 row-major (gemmT B)
#define OFF_TT    524288u     // bf16 [8][256][3072]   TT[b][e][r*512+i] = T_r[i][e]+relb_r[e]
#define OFF_WCT   6815744u    // bf16 [256][1536]      WcT[e][r*256+d] = relW[r][d][e]
#define OFF_WBT   7012352u    // bf16 [1024][256]      Wbig^T (c rows, k=d)
#define OFF_BB    7143424u    // fp32 [1024]           h1b|outb
#define OFF_REL   7144448u    // u8   [8][512][512]    relation codes (self=6)

// d_out layout (floats)
#define OUT0_OFF   0u        // output  [8][512][256]
#define INTERP_OFF 1048576u  // interp  [3][4096]
#define SYM_OFF    1060864u  // symbols [8][512][256]

__device__ __forceinline__ float gelu_exact(float x) {
    return 0.5f * x * (1.0f + erff(x * 0.70710678118654752f));
}

__device__ __forceinline__ ushort f2bf(float x) {
    __hip_bfloat16 h = __float2bfloat16(x);
    union { __hip_bfloat16 b; ushort u; } cv;
    cv.b = h;
    return cv.u;
}

// Branch-free classification (reference if/elif priority, applied in reverse).
__device__ __forceinline__ int rel_of(float dx, float dy) {
    int r = (fabsf(dx) < 0.3f && fabsf(dy) < 0.3f) ? 4 : 5;
    r = (dx >  0.5f) ? 3 : r;
    r = (dx < -0.5f) ? 2 : r;
    r = (dy < -0.5f) ? 1 : r;
    r = (dy >  0.5f) ? 0 : r;
    return r;
}

// ====== 64x64-tile MFMA core (4 waves 2x2), double-buffered LDS ===========
// = the 134.9 µs round-11 core with one fix: LDS cells XOR-SWIZZLED
// (cell(c,r) = c*64 + (r ^ (c<<1))). R16's counters proved the staging
// ds_writes (cell = sq*64+sm: 16-lane phase hits cells all = same mod 8 in
// groups of 4) were a 4-way bank conflict, 4.7M cycles/dispatch in agg.
// XOR with (c<<1) spreads write phases across all 8 bank-quartets (2-way,
// free per m136); reads permute within their aligned 16-cell group so they
// remain conflict-free (both-sides-same-involution, rule #21).
// Fragment layout (m89/m91 verified): A: m=lane&15,k=quad*8+j; B: n=lane&15;
// C/D: col=lane&15, row=quad*4+reg.
#define TILE_IDS()                                             \
    const int lane = tid & 63, w = tid >> 6;                   \
    const int wm = w >> 1, wn = w & 1;                         \
    const int quad = lane >> 4, l15 = lane & 15;               \
    const int sm = tid >> 2, sq = tid & 3;

#define LCELL(c, r) ((c) * 64 + ((r) ^ ((c) << 1)))

#define MFMA_STEP(Abuf, Bbuf)                                                \
    {                                                                        \
        short8 af[2], bfr[2];                                                \
        _Pragma("unroll")                                                    \
        for (int mt = 0; mt < 2; mt++)                                       \
            af[mt] = *(const short8*)&(Abuf)[LCELL(quad, wm * 32 + mt * 16 + l15) * 8]; \
        _Pragma("unroll")                                                    \
        for (int nt = 0; nt < 2; nt++)                                       \
            bfr[nt] = *(const short8*)&(Bbuf)[LCELL(quad, wn * 32 + nt * 16 + l15) * 8]; \
        _Pragma("unroll")                                                    \
        for (int mt = 0; mt < 2; mt++)                                       \
            _Pragma("unroll")                                                \
            for (int nt = 0; nt < 2; nt++)                                   \
                acc[mt][nt] = __builtin_amdgcn_mfma_f32_16x16x32_bf16(       \
                    af[mt], bfr[nt], acc[mt][nt], 0, 0, 0);                  \
    }

#define ACC_INIT()                                             \
    f32x4 acc[2][2];                                           \
    _Pragma("unroll") for (int mt = 0; mt < 2; mt++)           \
    _Pragma("unroll") for (int nt = 0; nt < 2; nt++)           \
        acc[mt][nt] = (f32x4){0.f, 0.f, 0.f, 0.f};

// front block ranges (round-11 verified, 134.9 µs)
#define FB_TILE  0      // 160 blocks: 64x64 transpose tiles (WcT 96, h1W 48, outW 16)
#define FB_OUTI  160    // 12 blocks:  outI init (float4)
#define FB_BBIG  172    // 1 block:    bbig init
#define FB_GATH  173    // 1024 blocks: gather (4 rows/block, float4)
#define FB_CLS   1197   // 512 blocks: classify
#define FB_TOTAL 1709

// ---------------------------------------------------------------- front ---
// [= round-11 verbatim]
__global__ __launch_bounds__(256) void front_kernel(
    const int* __restrict__ ids, const float* __restrict__ positions,
    const float* __restrict__ symt, const float* __restrict__ layt,
    const float* __restrict__ relW, const float* __restrict__ h1W,
    const float* __restrict__ outW, const float* __restrict__ h1b,
    const float* __restrict__ outb, const float* __restrict__ h2b,
    ushort* __restrict__ WcT, ushort* __restrict__ WbT,
    float* __restrict__ bbig, float* __restrict__ outI,
    float* __restrict__ symOut, ushort* __restrict__ s0b,
    unsigned char* __restrict__ rel)
{
    __shared__ float shbuf[64 * 65];    // 16.6 KB transpose tile / classify px,py
    int blk = blockIdx.x, tid = threadIdx.x;
    if (blk < FB_OUTI) {
        int kl = tid & 63, g4 = tid >> 6;
        const float* src; int srow, scol;
        ushort* dst; int drow, dstride, dcol;
        if (blk < 96) {                         // relW [1536][256] -> WcT[e][rd]
            int t = blk, rdt = t >> 2, et = t & 3;
            src = relW; srow = rdt * 64; scol = et * 64;
            dst = WcT; drow = et * 64; dstride = 1536; dcol = rdt * 64;
        } else if (blk < 144) {                 // h1W [r][256 d][256 e] -> WbT[r*256+e][d]
            int t = blk - 96, r = t >> 4, dt = (t >> 2) & 3, et = t & 3;
            src = h1W + (size_t)r * DD * DD; srow = dt * 64; scol = et * 64;
            dst = WbT; drow = r * 256 + et * 64; dstride = 256; dcol = dt * 64;
        } else {                                // outW [256 d][256 o] -> WbT[768+o][d]
            int t = blk - 144, dt = t >> 2, et = t & 3;
            src = outW; srow = dt * 64; scol = et * 64;
            dst = WbT; drow = 768 + et * 64; dstride = 256; dcol = dt * 64;
        }
#pragma unroll
        for (int p = 0; p < 16; p++) {
            int rl = p * 4 + g4;
            shbuf[rl * 65 + kl] = src[(size_t)(srow + rl) * 256 + scol + kl];
        }
        __syncthreads();
#pragma unroll
        for (int q = 0; q < 16; q++) {
            int el = q * 4 + g4;
            dst[(size_t)(drow + el) * dstride + dcol + kl] = f2bf(shbuf[kl * 65 + el]);
        }
    } else if (blk < FB_BBIG) {
        int idx = (blk - FB_OUTI) * 256 + tid;   // [0, 3072) float4s of outI
        float v = h2b[idx >> 10];
        ((float4*)outI)[idx] = (float4){v, v, v, v};
    } else if (blk < FB_GATH) {
        ((float4*)bbig)[tid] = (tid < 192) ? ((const float4*)h1b)[tid]
                                           : ((const float4*)outb)[tid - 192];
    } else if (blk < FB_CLS) {
        int row = (blk - FB_GATH) * 4 + (tid >> 6); // 4 rows/block
        int d = (tid & 63) * 4;
        int id = ids[row];
        float4 a = *(const float4*)&symt[(size_t)id * DD + d];
        float4 c = *(const float4*)&layt[(size_t)id * DD + d];
        float4 v = {a.x + c.x, a.y + c.y, a.z + c.z, a.w + c.w};
        *(float4*)&symOut[(size_t)row * DD + d] = v;
        union { ushort u[4]; uint2 q; } p;
        p.u[0] = f2bf(v.x); p.u[1] = f2bf(v.y); p.u[2] = f2bf(v.z); p.u[3] = f2bf(v.w);
        *(uint2*)&s0b[(size_t)row * DD + d] = p.q;
    } else {
        float* px = shbuf;
        float* py = shbuf + NN;
        int blk2 = blk - FB_CLS;                 // [0,512)
        int b = blk2 >> 6;
        int j0 = (blk2 & 63) << 3;
        int jl = tid >> 5, sub = tid & 31;       // 8 j's x 32 workers x 16 i's
        for (int i = tid; i < NN; i += 256) {
            float2 p = ((const float2*)positions)[b * NN + i];
            px[i] = p.x; py[i] = p.y;
        }
        __syncthreads();
        int j = j0 + jl;
        float xj = px[j], yj = py[j];
        union { unsigned char u8[16]; uint4 v; } codes;
#pragma unroll
        for (int t = 0; t < 16; t++) {
            int i = sub * 16 + t;
            int r = rel_of(xj - px[i], yj - py[i]);
            r = (i == j) ? 6 : r;
            codes.u8[t] = (unsigned char)r;
        }
        *(uint4*)&rel[((size_t)(b * NN + j)) * NN + sub * 16] = codes.v;
    }
}

// ----------------------------------------------------------------- gemmT --
// TT[b][e][r*512+i] = sum_d relW[r][d][e]*s0[b][i][d] + relb[r][e]
// Double-buffered; grid (8,24,8) = 1536 blocks.  [= round-11 + swizzle]
__global__ __launch_bounds__(256) void gemmT_kernel(
    const ushort* __restrict__ WcT, const ushort* __restrict__ s0b,
    const float* __restrict__ relb, ushort* __restrict__ TT)
{
    __shared__ ushort Als[2][2048], Bls[2][2048];
    int tid = threadIdx.x;
    int b = blockIdx.z;
    int rowM0 = blockIdx.y * 64;           // in [0,1536): r*256+e
    int col0 = blockIdx.x * 64;            // i tile
    int r = rowM0 >> 8, e0 = rowM0 & 255;
    TILE_IDS();
    ACC_INIT();
    const ushort* gA = WcT + (size_t)(e0 + sm) * 1536 + r * 256 + sq * 8;
    const ushort* gB = s0b + ((size_t)(b * NN) + col0 + sm) * DD + sq * 8;
    const int lo = LCELL(sq, sm) * 8;

    *(uint4*)&Als[0][lo] = *(const uint4*)gA;
    *(uint4*)&Bls[0][lo] = *(const uint4*)gB;
#pragma unroll
    for (int i = 0; i < 8; i++) {
        __syncthreads();
        uint4 av2, bv2;
        if (i < 7) {
            av2 = *(const uint4*)(gA + (i + 1) * 32);
            bv2 = *(const uint4*)(gB + (i + 1) * 32);
        }
        MFMA_STEP(Als[i & 1], Bls[i & 1]);
        if (i < 7) {
            *(uint4*)&Als[(i + 1) & 1][lo] = av2;
            *(uint4*)&Bls[(i + 1) & 1][lo] = bv2;
        }
    }
#pragma unroll
    for (int mt = 0; mt < 2; mt++)
#pragma unroll
        for (int nt = 0; nt < 2; nt++)
#pragma unroll
            for (int v = 0; v < 4; v++) {
                int e = e0 + wm * 32 + mt * 16 + quad * 4 + v;
                int i = col0 + wn * 32 + nt * 16 + l15;
                TT[((size_t)(b * DD) + e) * 3072 + r * 512 + i] =
                    f2bf(acc[mt][nt][v] + relb[r * DD + e]);
            }
}

// ------------------------------------------------------------- agg gemm ---
// symOut[b*512+j][e] += sum_{r,i} 1[rel(i,j)=r] * TT[b][e][r*512+i]
// One-hot A from u8 codes; 3 K-slices (r-pairs, K=1024), grid (4,8,24).
// Double-buffered; atomicAdd into symOut.  [= round-11 + swizzle]
__global__ __launch_bounds__(256) void agg_gemm(
    const unsigned char* __restrict__ rel, const ushort* __restrict__ TT,
    float* __restrict__ symOut)
{
    __shared__ ushort Als[2][2048], Bls[2][2048];
    int tid = threadIdx.x;
    int z = blockIdx.z;
    int b = z / 3, rg = z - b * 3;
    int row0 = blockIdx.y * 64, col0 = blockIdx.x * 64;
    TILE_IDS();
    ACC_INIT();
    const unsigned char* gC = rel + ((size_t)(b * NN + row0 + sm)) * NN;
    const ushort* gB = TT + ((size_t)(b * DD) + col0 + sm) * 3072 + rg * 1024 + sq * 8;
    const int lo = LCELL(sq, sm) * 8;

#define AGG_LOADS(i, cw, bv)                                        \
    cw = *(const uint2*)(gC + (((i) * 32 + sq * 8) & 511));         \
    bv = *(const uint4*)(gB + (i) * 32);

#define AGG_STAGE(i, cw, bv, buf)                                   \
    {                                                               \
        int rr_ = 2 * rg + (((i) * 32) >> 9);                       \
        union alignas(16) { ushort u[8]; uint4 v; } am;             \
        _Pragma("unroll")                                           \
        for (int t = 0; t < 8; t++) {                               \
            unsigned int word = (t < 4) ? cw.x : cw.y;              \
            unsigned int code = (word >> (8 * (t & 3))) & 255u;     \
            am.u[t] = (code == (unsigned)rr_) ? 0x3F80 : 0;         \
        }                                                           \
        *(uint4*)&Als[buf][lo] = am.v;                              \
        *(uint4*)&Bls[buf][lo] = bv;                                \
    }

    uint2 cw0; uint4 bv0;
    AGG_LOADS(0, cw0, bv0);
    AGG_STAGE(0, cw0, bv0, 0);
    for (int i = 0; i < 32; i++) {
        __syncthreads();
        uint2 cw2 = cw0; uint4 bv2 = bv0;
        if (i < 31) { AGG_LOADS(i + 1, cw2, bv2); }
        MFMA_STEP(Als[i & 1], Bls[i & 1]);
        if (i < 31) { AGG_STAGE(i + 1, cw2, bv2, (i + 1) & 1); }
    }
#undef AGG_LOADS
#undef AGG_STAGE
#pragma unroll
    for (int mt = 0; mt < 2; mt++)
#pragma unroll
        for (int nt = 0; nt < 2; nt++)
#pragma unroll
            for (int v = 0; v < 4; v++) {
                int j = row0 + wm * 32 + mt * 16 + quad * 4 + v;
                int e = col0 + wn * 32 + nt * 16 + l15;
                atomicAdd(&symOut[((size_t)(b * NN) + j) * DD + e], acc[mt][nt][v]);
            }
}

// ----------------------------------------------------------------- gemm2 --
// symOut(fp32, bf16 at staging) @ Wbig^T. Col tiles <768: gelu + fused
// interp reduce (atomicAdd into outI pre-loaded with h2b). Else: out0.
// [= round-11 + swizzle]
__global__ __launch_bounds__(256) void gemm2_kernel(
    const float* __restrict__ symOut, const ushort* __restrict__ WbT,
    const float* __restrict__ bbig, const float* __restrict__ h2W,
    float* __restrict__ out0, float* __restrict__ outI)
{
    __shared__ ushort Als[2][2048], Bls[2][2048];
    int tid = threadIdx.x;
    int row0 = blockIdx.y * 64, col0 = blockIdx.x * 64;
    TILE_IDS();
    ACC_INIT();
    const float*  gA = symOut + (size_t)(row0 + sm) * DD + sq * 8;
    const ushort* gB = WbT    + (size_t)(col0 + sm) * DD + sq * 8;
    const int lo = LCELL(sq, sm) * 8;

#define G2_LOADS(i, a0, a1, bv)                                     \
    a0 = *(const float4*)(gA + (i) * 32);                           \
    a1 = *(const float4*)(gA + (i) * 32 + 4);                       \
    bv = *(const uint4*)(gB + (i) * 32);

#define G2_STAGE(a0, a1, bv, buf)                                   \
    {                                                               \
        union alignas(16) { ushort u[8]; uint4 v; } am;             \
        am.u[0] = f2bf(a0.x); am.u[1] = f2bf(a0.y);                 \
        am.u[2] = f2bf(a0.z); am.u[3] = f2bf(a0.w);                 \
        am.u[4] = f2bf(a1.x); am.u[5] = f2bf(a1.y);                 \
        am.u[6] = f2bf(a1.z); am.u[7] = f2bf(a1.w);                 \
        *(uint4*)&Als[buf][lo] = am.v;                              \
        *(uint4*)&Bls[buf][lo] = bv;                                \
    }

    float4 a0, a1; uint4 bv;
    G2_LOADS(0, a0, a1, bv);
    G2_STAGE(a0, a1, bv, 0);
#pragma unroll
    for (int i = 0; i < 8; i++) {
        __syncthreads();
        float4 a0n = a0, a1n = a1; uint4 bvn = bv;
        if (i < 7) { G2_LOADS(i + 1, a0n, a1n, bvn); }
        MFMA_STEP(Als[i & 1], Bls[i & 1]);
        if (i < 7) { G2_STAGE(a0n, a1n, bvn, (i + 1) & 1); }
    }
#undef G2_LOADS
#undef G2_STAGE
    if (col0 >= 768) {
#pragma unroll
        for (int nt = 0; nt < 2; nt++) {
            int c = col0 + wn * 32 + nt * 16 + l15;
            float bb = bbig[c];
#pragma unroll
            for (int mt = 0; mt < 2; mt++)
#pragma unroll
                for (int v = 0; v < 4; v++) {
                    int row = row0 + wm * 32 + mt * 16 + quad * 4 + v;
                    out0[(size_t)row * DD + (c - 768)] = acc[mt][nt][v] + bb;
                }
        }
    } else {
        int head = col0 >> 8;
        float part[2][4];
#pragma unroll
        for (int mt = 0; mt < 2; mt++)
#pragma unroll
            for (int v = 0; v < 4; v++) part[mt][v] = 0.f;
#pragma unroll
        for (int nt = 0; nt < 2; nt++) {
            int c = col0 + wn * 32 + nt * 16 + l15;
            float bb = bbig[c];
            float w2 = h2W[c];
#pragma unroll
            for (int mt = 0; mt < 2; mt++)
#pragma unroll
                for (int v = 0; v < 4; v++)
                    part[mt][v] += gelu_exact(acc[mt][nt][v] + bb) * w2;
        }
#pragma unroll
        for (int mt = 0; mt < 2; mt++)
#pragma unroll
            for (int v = 0; v < 4; v++) {
                float p = part[mt][v];
                p += __shfl_xor(p, 1); p += __shfl_xor(p, 2);
                p += __shfl_xor(p, 4); p += __shfl_xor(p, 8);
                if (l15 == 0) {
                    int row = row0 + wm * 32 + mt * 16 + quad * 4 + v;
                    atomicAdd(&outI[head * BNT + row], p);
                }
            }
    }
}

// ---------------------------------------------------------------- launch --
extern "C" void kernel_launch(void* const* d_in, const int* in_sizes, int n_in,
                              void* d_out, int out_size, void* d_ws, size_t ws_size,
                              hipStream_t stream)
{
    const int*   ids  = (const int*)d_in[0];
    const float* pos  = (const float*)d_in[1];
    const float* symt = (const float*)d_in[2];
    const float* layt = (const float*)d_in[3];
    const float* relW = (const float*)d_in[4];
    const float* relb = (const float*)d_in[5];
    const float* h1W  = (const float*)d_in[6];
    const float* h1b  = (const float*)d_in[7];
    const float* h2W  = (const float*)d_in[8];
    const float* h2b  = (const float*)d_in[9];
    const float* outW = (const float*)d_in[10];
    const float* outb = (const float*)d_in[11];
    float* out = (float*)d_out;
    float* ws  = (float*)d_ws;

    ushort* s0b  = (ushort*)(ws + OFF_S0B);
    ushort* TT   = (ushort*)(ws + OFF_TT);
    ushort* WcT  = (ushort*)(ws + OFF_WCT);
    ushort* WbT  = (ushort*)(ws + OFF_WBT);
    float*  bbig = ws + OFF_BB;
    unsigned char* rel = (unsigned char*)(ws + OFF_REL);

    front_kernel<<<FB_TOTAL, 256, 0, stream>>>(ids, pos, symt, layt, relW, h1W, outW,
                                               h1b, outb, h2b, WcT, WbT, bbig,
                                               out + INTERP_OFF, out + SYM_OFF, s0b, rel);
    gemmT_kernel<<<dim3(8, 24, 8), 256, 0, stream>>>(WcT, s0b, relb, TT);
    agg_gemm<<<dim3(4, 8, 24), 256, 0, stream>>>(rel, TT, out + SYM_OFF);
    gemm2_kernel<<<dim3(16, 64), 256, 0, stream>>>(out + SYM_OFF, WbT,
                                                   bbig, h2W,
                                                   out + OUT0_OFF, out + INTERP_OFF);
}

// Round 18
// 131.937 us; speedup vs baseline: 1.3535x; 1.0020x over previous
//
#include <hip/hip_runtime.h>
#include <hip/hip_bf16.h>
#include <math.h>

#define BB 8
#define NN 512
#define DD 256
#define BNT 4096   // B*N

typedef __attribute__((ext_vector_type(8))) short short8;
typedef __attribute__((ext_vector_type(4))) float f32x4;

// Workspace layout (float offsets). ~18 MB.
// TT layout (NEW): [b][r][ib(16)][e(256)][ii(32)] bf16 — element
// (b,r,ib,e,ii) = old TT[b][e][r*512+ib*32+ii]. agg's per-K-step B tile
// (64 e x 32 i) is now CONTIGUOUS (4 KB), one wave-load = 1 KB contiguous.
#define OFF_S0B   0u          // bf16 [4096][256]      s0 row-major (gemmT B)
#define OFF_TT    524288u     // bf16 [8][96][8192]    (see above) 12.6 MB
#define OFF_WCT   6815744u    // bf16 [256][1536]      WcT[e][r*256+d] = relW[r][d][e]
#define OFF_WBT   7012352u    // bf16 [1024][256]      Wbig^T (c rows, k=d)
#define OFF_BB    7143424u    // fp32 [1024]           h1b|outb
#define OFF_REL   7144448u    // u8   [8][512][512]    relation codes (self=6)

// d_out layout (floats)
#define OUT0_OFF   0u        // output  [8][512][256]
#define INTERP_OFF 1048576u  // interp  [3][4096]
#define SYM_OFF    1060864u  // symbols [8][512][256]

__device__ __forceinline__ float gelu_exact(float x) {
    return 0.5f * x * (1.0f + erff(x * 0.70710678118654752f));
}

__device__ __forceinline__ ushort f2bf(float x) {
    __hip_bfloat16 h = __float2bfloat16(x);
    union { __hip_bfloat16 b; ushort u; } cv;
    cv.b = h;
    return cv.u;
}

// Branch-free classification (reference if/elif priority, applied in reverse).
__device__ __forceinline__ int rel_of(float dx, float dy) {
    int r = (fabsf(dx) < 0.3f && fabsf(dy) < 0.3f) ? 4 : 5;
    r = (dx >  0.5f) ? 3 : r;
    r = (dx < -0.5f) ? 2 : r;
    r = (dy < -0.5f) ? 1 : r;
    r = (dy >  0.5f) ? 0 : r;
    return r;
}

// ====== 64x64-tile MFMA core (4 waves 2x2), double-buffered LDS ===========
// = the 132.2 µs round-17 core (XOR-swizzled LDS cells; write phases 2-way,
// reads conflict-free). Fragment layout (m89/m91 verified):
// A: m=lane&15,k=quad*8+j; B: n=lane&15; C/D: col=lane&15, row=quad*4+reg.
#define TILE_IDS()                                             \
    const int lane = tid & 63, w = tid >> 6;                   \
    const int wm = w >> 1, wn = w & 1;                         \
    const int quad = lane >> 4, l15 = lane & 15;               \
    const int sm = tid >> 2, sq = tid & 3;

#define LCELL(c, r) ((c) * 64 + ((r) ^ ((c) << 1)))

#define MFMA_STEP(Abuf, Bbuf)                                                \
    {                                                                        \
        short8 af[2], bfr[2];                                                \
        _Pragma("unroll")                                                    \
        for (int mt = 0; mt < 2; mt++)                                       \
            af[mt] = *(const short8*)&(Abuf)[LCELL(quad, wm * 32 + mt * 16 + l15) * 8]; \
        _Pragma("unroll")                                                    \
        for (int nt = 0; nt < 2; nt++)                                       \
            bfr[nt] = *(const short8*)&(Bbuf)[LCELL(quad, wn * 32 + nt * 16 + l15) * 8]; \
        _Pragma("unroll")                                                    \
        for (int mt = 0; mt < 2; mt++)                                       \
            _Pragma("unroll")                                                \
            for (int nt = 0; nt < 2; nt++)                                   \
                acc[mt][nt] = __builtin_amdgcn_mfma_f32_16x16x32_bf16(       \
                    af[mt], bfr[nt], acc[mt][nt], 0, 0, 0);                  \
    }

#define ACC_INIT()                                             \
    f32x4 acc[2][2];                                           \
    _Pragma("unroll") for (int mt = 0; mt < 2; mt++)           \
    _Pragma("unroll") for (int nt = 0; nt < 2; nt++)           \
        acc[mt][nt] = (f32x4){0.f, 0.f, 0.f, 0.f};

// front block ranges (round-11/17 verified)
#define FB_TILE  0      // 160 blocks: 64x64 transpose tiles (WcT 96, h1W 48, outW 16)
#define FB_OUTI  160    // 12 blocks:  outI init (float4)
#define FB_BBIG  172    // 1 block:    bbig init
#define FB_GATH  173    // 1024 blocks: gather (4 rows/block, float4)
#define FB_CLS   1197   // 512 blocks: classify
#define FB_TOTAL 1709

// ---------------------------------------------------------------- front ---
// [= round-17 verbatim]
__global__ __launch_bounds__(256) void front_kernel(
    const int* __restrict__ ids, const float* __restrict__ positions,
    const float* __restrict__ symt, const float* __restrict__ layt,
    const float* __restrict__ relW, const float* __restrict__ h1W,
    const float* __restrict__ outW, const float* __restrict__ h1b,
    const float* __restrict__ outb, const float* __restrict__ h2b,
    ushort* __restrict__ WcT, ushort* __restrict__ WbT,
    float* __restrict__ bbig, float* __restrict__ outI,
    float* __restrict__ symOut, ushort* __restrict__ s0b,
    unsigned char* __restrict__ rel)
{
    __shared__ float shbuf[64 * 65];    // 16.6 KB transpose tile / classify px,py
    int blk = blockIdx.x, tid = threadIdx.x;
    if (blk < FB_OUTI) {
        int kl = tid & 63, g4 = tid >> 6;
        const float* src; int srow, scol;
        ushort* dst; int drow, dstride, dcol;
        if (blk < 96) {                         // relW [1536][256] -> WcT[e][rd]
            int t = blk, rdt = t >> 2, et = t & 3;
            src = relW; srow = rdt * 64; scol = et * 64;
            dst = WcT; drow = et * 64; dstride = 1536; dcol = rdt * 64;
        } else if (blk < 144) {                 // h1W [r][256 d][256 e] -> WbT[r*256+e][d]
            int t = blk - 96, r = t >> 4, dt = (t >> 2) & 3, et = t & 3;
            src = h1W + (size_t)r * DD * DD; srow = dt * 64; scol = et * 64;
            dst = WbT; drow = r * 256 + et * 64; dstride = 256; dcol = dt * 64;
        } else {                                // outW [256 d][256 o] -> WbT[768+o][d]
            int t = blk - 144, dt = t >> 2, et = t & 3;
            src = outW; srow = dt * 64; scol = et * 64;
            dst = WbT; drow = 768 + et * 64; dstride = 256; dcol = dt * 64;
        }
#pragma unroll
        for (int p = 0; p < 16; p++) {
            int rl = p * 4 + g4;
            shbuf[rl * 65 + kl] = src[(size_t)(srow + rl) * 256 + scol + kl];
        }
        __syncthreads();
#pragma unroll
        for (int q = 0; q < 16; q++) {
            int el = q * 4 + g4;
            dst[(size_t)(drow + el) * dstride + dcol + kl] = f2bf(shbuf[kl * 65 + el]);
        }
    } else if (blk < FB_BBIG) {
        int idx = (blk - FB_OUTI) * 256 + tid;   // [0, 3072) float4s of outI
        float v = h2b[idx >> 10];
        ((float4*)outI)[idx] = (float4){v, v, v, v};
    } else if (blk < FB_GATH) {
        ((float4*)bbig)[tid] = (tid < 192) ? ((const float4*)h1b)[tid]
                                           : ((const float4*)outb)[tid - 192];
    } else if (blk < FB_CLS) {
        int row = (blk - FB_GATH) * 4 + (tid >> 6); // 4 rows/block
        int d = (tid & 63) * 4;
        int id = ids[row];
        float4 a = *(const float4*)&symt[(size_t)id * DD + d];
        float4 c = *(const float4*)&layt[(size_t)id * DD + d];
        float4 v = {a.x + c.x, a.y + c.y, a.z + c.z, a.w + c.w};
        *(float4*)&symOut[(size_t)row * DD + d] = v;
        union { ushort u[4]; uint2 q; } p;
        p.u[0] = f2bf(v.x); p.u[1] = f2bf(v.y); p.u[2] = f2bf(v.z); p.u[3] = f2bf(v.w);
        *(uint2*)&s0b[(size_t)row * DD + d] = p.q;
    } else {
        float* px = shbuf;
        float* py = shbuf + NN;
        int blk2 = blk - FB_CLS;                 // [0,512)
        int b = blk2 >> 6;
        int j0 = (blk2 & 63) << 3;
        int jl = tid >> 5, sub = tid & 31;       // 8 j's x 32 workers x 16 i's
        for (int i = tid; i < NN; i += 256) {
            float2 p = ((const float2*)positions)[b * NN + i];
            px[i] = p.x; py[i] = p.y;
        }
        __syncthreads();
        int j = j0 + jl;
        float xj = px[j], yj = py[j];
        union { unsigned char u8[16]; uint4 v; } codes;
#pragma unroll
        for (int t = 0; t < 16; t++) {
            int i = sub * 16 + t;
            int r = rel_of(xj - px[i], yj - py[i]);
            r = (i == j) ? 6 : r;
            codes.u8[t] = (unsigned char)r;
        }
        *(uint4*)&rel[((size_t)(b * NN + j)) * NN + sub * 16] = codes.v;
    }
}

// ----------------------------------------------------------------- gemmT --
// TT(b,r,ib,e,ii) = sum_d relW[r][d][e]*s0[b][i][d] + relb[r][e],
// i = ib*32+ii.  Double-buffered; grid (8,24,8) = 1536 blocks.
// [= round-17 + new TT store indexing]
__global__ __launch_bounds__(256) void gemmT_kernel(
    const ushort* __restrict__ WcT, const ushort* __restrict__ s0b,
    const float* __restrict__ relb, ushort* __restrict__ TT)
{
    __shared__ ushort Als[2][2048], Bls[2][2048];
    int tid = threadIdx.x;
    int b = blockIdx.z;
    int rowM0 = blockIdx.y * 64;           // in [0,1536): r*256+e
    int col0 = blockIdx.x * 64;            // i tile
    int r = rowM0 >> 8, e0 = rowM0 & 255;
    TILE_IDS();
    ACC_INIT();
    const ushort* gA = WcT + (size_t)(e0 + sm) * 1536 + r * 256 + sq * 8;
    const ushort* gB = s0b + ((size_t)(b * NN) + col0 + sm) * DD + sq * 8;
    const int lo = LCELL(sq, sm) * 8;

    *(uint4*)&Als[0][lo] = *(const uint4*)gA;
    *(uint4*)&Bls[0][lo] = *(const uint4*)gB;
#pragma unroll
    for (int i = 0; i < 8; i++) {
        __syncthreads();
        uint4 av2, bv2;
        if (i < 7) {
            av2 = *(const uint4*)(gA + (i + 1) * 32);
            bv2 = *(const uint4*)(gB + (i + 1) * 32);
        }
        MFMA_STEP(Als[i & 1], Bls[i & 1]);
        if (i < 7) {
            *(uint4*)&Als[(i + 1) & 1][lo] = av2;
            *(uint4*)&Bls[(i + 1) & 1][lo] = bv2;
        }
    }
    // store: flat block = b*96 + r*16 + (col0>>5) + wn; offset e*32 + ii
#pragma unroll
    for (int nt = 0; nt < 2; nt++) {
        ushort* dst = TT + (size_t)(b * 96 + r * 16 + (col0 >> 5) + wn) * 8192
                      + nt * 16 + l15;
#pragma unroll
        for (int mt = 0; mt < 2; mt++)
#pragma unroll
            for (int v = 0; v < 4; v++) {
                int e = e0 + wm * 32 + mt * 16 + quad * 4 + v;
                dst[(size_t)e * 32] = f2bf(acc[mt][nt][v] + relb[r * DD + e]);
            }
    }
}

// ------------------------------------------------------------- agg gemm ---
// symOut[b*512+j][e] += sum_{r,i} 1[rel(i,j)=r] * T_r[i][e]
// One-hot A from u8 codes; 3 K-slices (r-pairs, K=1024), grid (4,8,24).
// B tile per K-step = ONE contiguous 4 KB block (new TT layout):
// gB + i*8192 with flat base b*96+rg*32.  [= round-17 + new TT load]
__global__ __launch_bounds__(256) void agg_gemm(
    const unsigned char* __restrict__ rel, const ushort* __restrict__ TT,
    float* __restrict__ symOut)
{
    __shared__ ushort Als[2][2048], Bls[2][2048];
    int tid = threadIdx.x;
    int z = blockIdx.z;
    int b = z / 3, rg = z - b * 3;
    int row0 = blockIdx.y * 64, col0 = blockIdx.x * 64;
    TILE_IDS();
    ACC_INIT();
    const unsigned char* gC = rel + ((size_t)(b * NN + row0 + sm)) * NN;
    const ushort* gB = TT + (size_t)(b * 96 + rg * 32) * 8192
                       + (col0 + sm) * 32 + sq * 8;
    const int lo = LCELL(sq, sm) * 8;

#define AGG_LOADS(i, cw, bv)                                        \
    cw = *(const uint2*)(gC + (((i) * 32 + sq * 8) & 511));         \
    bv = *(const uint4*)(gB + (size_t)(i) * 8192);

#define AGG_STAGE(i, cw, bv, buf)                                   \
    {                                                               \
        int rr_ = 2 * rg + (((i) * 32) >> 9);                       \
        union alignas(16) { ushort u[8]; uint4 v; } am;             \
        _Pragma("unroll")                                           \
        for (int t = 0; t < 8; t++) {                               \
            unsigned int word = (t < 4) ? cw.x : cw.y;              \
            unsigned int code = (word >> (8 * (t & 3))) & 255u;     \
            am.u[t] = (code == (unsigned)rr_) ? 0x3F80 : 0;         \
        }                                                           \
        *(uint4*)&Als[buf][lo] = am.v;                              \
        *(uint4*)&Bls[buf][lo] = bv;                                \
    }

    uint2 cw0; uint4 bv0;
    AGG_LOADS(0, cw0, bv0);
    AGG_STAGE(0, cw0, bv0, 0);
    for (int i = 0; i < 32; i++) {
        __syncthreads();
        uint2 cw2 = cw0; uint4 bv2 = bv0;
        if (i < 31) { AGG_LOADS(i + 1, cw2, bv2); }
        MFMA_STEP(Als[i & 1], Bls[i & 1]);
        if (i < 31) { AGG_STAGE(i + 1, cw2, bv2, (i + 1) & 1); }
    }
#undef AGG_LOADS
#undef AGG_STAGE
#pragma unroll
    for (int mt = 0; mt < 2; mt++)
#pragma unroll
        for (int nt = 0; nt < 2; nt++)
#pragma unroll
            for (int v = 0; v < 4; v++) {
                int j = row0 + wm * 32 + mt * 16 + quad * 4 + v;
                int e = col0 + wn * 32 + nt * 16 + l15;
                atomicAdd(&symOut[((size_t)(b * NN) + j) * DD + e], acc[mt][nt][v]);
            }
}

// ----------------------------------------------------------------- gemm2 --
// symOut(fp32, bf16 at staging) @ Wbig^T. Col tiles <768: gelu + fused
// interp reduce (atomicAdd into outI pre-loaded with h2b). Else: out0.
// [= round-17 verbatim]
__global__ __launch_bounds__(256) void gemm2_kernel(
    const float* __restrict__ symOut, const ushort* __restrict__ WbT,
    const float* __restrict__ bbig, const float* __restrict__ h2W,
    float* __restrict__ out0, float* __restrict__ outI)
{
    __shared__ ushort Als[2][2048], Bls[2][2048];
    int tid = threadIdx.x;
    int row0 = blockIdx.y * 64, col0 = blockIdx.x * 64;
    TILE_IDS();
    ACC_INIT();
    const float*  gA = symOut + (size_t)(row0 + sm) * DD + sq * 8;
    const ushort* gB = WbT    + (size_t)(col0 + sm) * DD + sq * 8;
    const int lo = LCELL(sq, sm) * 8;

#define G2_LOADS(i, a0, a1, bv)                                     \
    a0 = *(const float4*)(gA + (i) * 32);                           \
    a1 = *(const float4*)(gA + (i) * 32 + 4);                       \
    bv = *(const uint4*)(gB + (i) * 32);

#define G2_STAGE(a0, a1, bv, buf)                                   \
    {                                                               \
        union alignas(16) { ushort u[8]; uint4 v; } am;             \
        am.u[0] = f2bf(a0.x); am.u[1] = f2bf(a0.y);                 \
        am.u[2] = f2bf(a0.z); am.u[3] = f2bf(a0.w);                 \
        am.u[4] = f2bf(a1.x); am.u[5] = f2bf(a1.y);                 \
        am.u[6] = f2bf(a1.z); am.u[7] = f2bf(a1.w);                 \
        *(uint4*)&Als[buf][lo] = am.v;                              \
        *(uint4*)&Bls[buf][lo] = bv;                                \
    }

    float4 a0, a1; uint4 bv;
    G2_LOADS(0, a0, a1, bv);
    G2_STAGE(a0, a1, bv, 0);
#pragma unroll
    for (int i = 0; i < 8; i++) {
        __syncthreads();
        float4 a0n = a0, a1n = a1; uint4 bvn = bv;
        if (i < 7) { G2_LOADS(i + 1, a0n, a1n, bvn); }
        MFMA_STEP(Als[i & 1], Bls[i & 1]);
        if (i < 7) { G2_STAGE(a0n, a1n, bvn, (i + 1) & 1); }
    }
#undef G2_LOADS
#undef G2_STAGE
    if (col0 >= 768) {
#pragma unroll
        for (int nt = 0; nt < 2; nt++) {
            int c = col0 + wn * 32 + nt * 16 + l15;
            float bb = bbig[c];
#pragma unroll
            for (int mt = 0; mt < 2; mt++)
#pragma unroll
                for (int v = 0; v < 4; v++) {
                    int row = row0 + wm * 32 + mt * 16 + quad * 4 + v;
                    out0[(size_t)row * DD + (c - 768)] = acc[mt][nt][v] + bb;
                }
        }
    } else {
        int head = col0 >> 8;
        float part[2][4];
#pragma unroll
        for (int mt = 0; mt < 2; mt++)
#pragma unroll
            for (int v = 0; v < 4; v++) part[mt][v] = 0.f;
#pragma unroll
        for (int nt = 0; nt < 2; nt++) {
            int c = col0 + wn * 32 + nt * 16 + l15;
            float bb = bbig[c];
            float w2 = h2W[c];
#pragma unroll
            for (int mt = 0; mt < 2; mt++)
#pragma unroll
                for (int v = 0; v < 4; v++)
                    part[mt][v] += gelu_exact(acc[mt][nt][v] + bb) * w2;
        }
#pragma unroll
        for (int mt = 0; mt < 2; mt++)
#pragma unroll
            for (int v = 0; v < 4; v++) {
                float p = part[mt][v];
                p += __shfl_xor(p, 1); p += __shfl_xor(p, 2);
                p += __shfl_xor(p, 4); p += __shfl_xor(p, 8);
                if (l15 == 0) {
                    int row = row0 + wm * 32 + mt * 16 + quad * 4 + v;
                    atomicAdd(&outI[head * BNT + row], p);
                }
            }
    }
}

// ---------------------------------------------------------------- launch --
extern "C" void kernel_launch(void* const* d_in, const int* in_sizes, int n_in,
                              void* d_out, int out_size, void* d_ws, size_t ws_size,
                              hipStream_t stream)
{
    const int*   ids  = (const int*)d_in[0];
    const float* pos  = (const float*)d_in[1];
    const float* symt = (const float*)d_in[2];
    const float* layt = (const float*)d_in[3];
    const float* relW = (const float*)d_in[4];
    const float* relb = (const float*)d_in[5];
    const float* h1W  = (const float*)d_in[6];
    const float* h1b  = (const float*)d_in[7];
    const float* h2W  = (const float*)d_in[8];
    const float* h2b  = (const float*)d_in[9];
    const float* outW = (const float*)d_in[10];
    const float* outb = (const float*)d_in[11];
    float* out = (float*)d_out;
    float* ws  = (float*)d_ws;

    ushort* s0b  = (ushort*)(ws + OFF_S0B);
    ushort* TT   = (ushort*)(ws + OFF_TT);
    ushort* WcT  = (ushort*)(ws + OFF_WCT);
    ushort* WbT  = (ushort*)(ws + OFF_WBT);
    float*  bbig = ws + OFF_BB;
    unsigned char* rel = (unsigned char*)(ws + OFF_REL);

    front_kernel<<<FB_TOTAL, 256, 0, stream>>>(ids, pos, symt, layt, relW, h1W, outW,
                                               h1b, outb, h2b, WcT, WbT, bbig,
                                               out + INTERP_OFF, out + SYM_OFF, s0b, rel);
    gemmT_kernel<<<dim3(8, 24, 8), 256, 0, stream>>>(WcT, s0b, relb, TT);
    agg_gemm<<<dim3(4, 8, 24), 256, 0, stream>>>(rel, TT, out + SYM_OFF);
    gemm2_kernel<<<dim3(16, 64), 256, 0, stream>>>(out + SYM_OFF, WbT,
                                                   bbig, h2W,
                                                   out + OUT0_OFF, out + INTERP_OFF);
}